// Round 3
// baseline (374.511 us; speedup 1.0000x reference)
//
#include <hip/hip_runtime.h>

#define IN_DIM  256
#define OUT_DIM 128
#define B_ROWS  4096
#define N_COLS  8192
#define ALPHA   0.2f

#define BT 16        // attention rows per block
#define NC 256       // n-chunk per phase
#define NPAD 24      // row stride 280 u16 = 560 B = 35*16 (b128-aligned, 2-way banks only)
#define CHUNKS (N_COLS / NC)   // 32

typedef unsigned short u16;
typedef unsigned int   u32;
typedef __attribute__((ext_vector_type(8))) short short8;
typedef __attribute__((ext_vector_type(4))) float floatx4;

__device__ __forceinline__ float bf2f(u16 v){ return __uint_as_float(((u32)v) << 16); }
__device__ __forceinline__ float bflo(u32 v){ return __uint_as_float(v << 16); }
__device__ __forceinline__ float bfhi(u32 v){ return __uint_as_float(v & 0xffff0000u); }
__device__ __forceinline__ u16 f2bf(float f){
    u32 u = __float_as_uint(f);
    u += 0x7fffu + ((u >> 16) & 1u);       // round-to-nearest-even
    return (u16)(u >> 16);
}

// ---------- dtype detection: bf16-packed vs float32 ----------
// f32 N(0,1): bits 7..14 are interior mantissa bits -> uniform, ~12% in [110,140].
// bf16 pairs: bits 7..14 are the LOW bf16's exponent -> ~97% in [110,140].
__global__ __launch_bounds__(256) void k_detect(const u32* __restrict__ g, int* __restrict__ flag){
    __shared__ int votes[256];
    int t = threadIdx.x;
    u32 u = g[t];
    int e = (u >> 7) & 0xFF;
    votes[t] = (e >= 110 && e <= 140) ? 1 : 0;
    __syncthreads();
    for (int s = 128; s > 0; s >>= 1){
        if (t < s) votes[t] += votes[t + s];
        __syncthreads();
    }
    if (t == 0) flag[0] = (votes[0] >= 128) ? 1 : 0;   // 1 = bf16
}

// ---------------- Wa1 = W @ a1  (256 floats) ----------------
__global__ __launch_bounds__(256) void k_wa(const void* __restrict__ W, const void* __restrict__ a1,
                                            const int* __restrict__ flag, float* __restrict__ Wa1){
    __shared__ float a1s[OUT_DIM];
    int t = threadIdx.x;
    const int isbf = *flag;
    if (t < OUT_DIM) a1s[t] = isbf ? bf2f(((const u16*)a1)[t]) : ((const float*)a1)[t];
    __syncthreads();
    float s = 0.f;
    if (isbf){
        const u32* wr = (const u32*)W + t * (OUT_DIM/2);
#pragma unroll 8
        for (int i = 0; i < OUT_DIM/2; i++){
            u32 g = wr[i];
            s += bflo(g) * a1s[2*i] + bfhi(g) * a1s[2*i+1];
        }
    } else {
        const float* wr = (const float*)W + t * OUT_DIM;
#pragma unroll 8
        for (int c = 0; c < OUT_DIM; c++) s += wr[c] * a1s[c];
    }
    Wa1[t] = s;
}

// ------------- h_neigh = gf[uniq] @ W -> bf16 blocked hB + s_neigh = h @ a2 -------------
// hB layout: u16 hB[(n>>3)*128*8 + c*8 + (n&7)]  (B-frag friendly: 16B per (kblock, col))
__global__ __launch_bounds__(128) void k_hneigh(const void* __restrict__ gf, const int* __restrict__ uniq,
                                                const void* __restrict__ W, const void* __restrict__ a2,
                                                const int* __restrict__ flag,
                                                u16* __restrict__ hB, float* __restrict__ s_neigh){
    const int c  = threadIdx.x;           // output column 0..127
    const int n0 = blockIdx.x * 8;        // 8 neighbor rows per block
    const int isbf = *flag;
    float acc[8] = {0.f,0.f,0.f,0.f,0.f,0.f,0.f,0.f};

    if (isbf){
        const u16* gfB = (const u16*)gf;
        const u32* gr[8];
#pragma unroll
        for (int r = 0; r < 8; r++)
            gr[r] = (const u32*)(gfB + (size_t)uniq[n0 + r] * IN_DIM);
        const u16* Wp = (const u16*)W + c;
        for (int k2 = 0; k2 < IN_DIM/2; k2++){
            float w0 = bf2f(Wp[(2*k2)   * OUT_DIM]);
            float w1 = bf2f(Wp[(2*k2+1) * OUT_DIM]);
#pragma unroll
            for (int r = 0; r < 8; r++){
                u32 g = gr[r][k2];
                acc[r] += bflo(g) * w0 + bfhi(g) * w1;
            }
        }
    } else {
        const float* gfF = (const float*)gf;
        const float2* gr[8];
#pragma unroll
        for (int r = 0; r < 8; r++)
            gr[r] = (const float2*)(gfF + (size_t)uniq[n0 + r] * IN_DIM);
        const float* Wp = (const float*)W + c;
        for (int k2 = 0; k2 < IN_DIM/2; k2++){
            float w0 = Wp[(2*k2)   * OUT_DIM];
            float w1 = Wp[(2*k2+1) * OUT_DIM];
#pragma unroll
            for (int r = 0; r < 8; r++){
                float2 g = gr[r][k2];
                acc[r] += g.x * w0 + g.y * w1;
            }
        }
    }

    // store 8 rows for this column: 16B contiguous, fully coalesced
    u32 pk[4];
#pragma unroll
    for (int i = 0; i < 4; i++)
        pk[i] = (u32)f2bf(acc[2*i]) | ((u32)f2bf(acc[2*i+1]) << 16);
    uint4 v; v.x = pk[0]; v.y = pk[1]; v.z = pk[2]; v.w = pk[3];
    ((uint4*)hB)[blockIdx.x * OUT_DIM + c] = v;

    // s_neigh[n] = sum_c h[n][c] * a2[c]
    float a2f = isbf ? bf2f(((const u16*)a2)[c]) : ((const float*)a2)[c];
    __shared__ float red[2][8];
    int lane = threadIdx.x & 63, wv = threadIdx.x >> 6;
#pragma unroll
    for (int r = 0; r < 8; r++){
        float p = acc[r] * a2f;
        for (int off = 32; off > 0; off >>= 1) p += __shfl_down(p, off);
        if (lane == 0) red[wv][r] = p;
    }
    __syncthreads();
    if (threadIdx.x < 8) s_neigh[n0 + threadIdx.x] = red[0][threadIdx.x] + red[1][threadIdx.x];
}

// ---------------- s_node[b] = gf[nodes[b]] . Wa1 ----------------
__global__ __launch_bounds__(256) void k_snode(const void* __restrict__ gf, const int* __restrict__ nodes,
                                               const float* __restrict__ Wa1, const int* __restrict__ flag,
                                               float* __restrict__ s_node){
    int lane = threadIdx.x & 63, wv = threadIdx.x >> 6;
    int b = blockIdx.x * 4 + wv;
    const int isbf = *flag;
    float4 wa = ((const float4*)Wa1)[lane];
    float x0, x1, x2, x3;
    if (isbf){
        uint2 gg = ((const uint2*)((const u16*)gf + (size_t)nodes[b] * IN_DIM))[lane];
        x0 = bflo(gg.x); x1 = bfhi(gg.x); x2 = bflo(gg.y); x3 = bfhi(gg.y);
    } else {
        float4 gg = ((const float4*)((const float*)gf + (size_t)nodes[b] * IN_DIM))[lane];
        x0 = gg.x; x1 = gg.y; x2 = gg.z; x3 = gg.w;
    }
    float s = x0*wa.x + x1*wa.y + x2*wa.z + x3*wa.w;
    for (int off = 32; off > 0; off >>= 1) s += __shfl_down(s, off);
    if (lane == 0) s_node[b] = s;
}

// -------- main: out[b][c] = normalize_row( sum_n p(b,n) * h[n][c] ), fused --------
// 512 threads = 8 waves; each wave owns 16 output columns; block owns 16 full rows.
__global__ __launch_bounds__(512) void k_attn(const int* __restrict__ mask,
                                              const float* __restrict__ s_node,
                                              const float* __restrict__ s_neigh,
                                              const u16* __restrict__ hB,
                                              const int* __restrict__ flag,
                                              void* __restrict__ out){
    const int b0   = blockIdx.x * BT;
    const int t    = threadIdx.x;
    const int lane = t & 63;
    const int wv   = t >> 6;                      // 0..7
    const int q    = lane >> 4;
    const int m    = lane & 15;
    const int c0   = wv * 16;                     // wave's output columns

    __shared__ __align__(16) u16 p_lds[BT][NC + NPAD];
    __shared__ float rs[8][BT];

    floatx4 acc = {0.f,0.f,0.f,0.f};

    float sn[2];
#pragma unroll
    for (int k = 0; k < 2; k++) sn[k] = s_node[b0 + wv + 8*k];

    // prefetch chunk 0
    int4 mreg[2];
    float4 sreg;
#pragma unroll
    for (int k = 0; k < 2; k++)
        mreg[k] = *(const int4*)(mask + (size_t)(b0 + wv + 8*k) * N_COLS + lane*4);
    sreg = *(const float4*)(s_neigh + lane*4);

    for (int ch = 0; ch < CHUNKS; ch++){
        // ---- phase 1: p = mask ? exp(lrelu(s_node+s_neigh)) : 0, bf16 into LDS ----
#pragma unroll
        for (int k = 0; k < 2; k++){
            const int r = wv + 8*k;
            float e0 = sn[k] + sreg.x, e1 = sn[k] + sreg.y;
            float e2 = sn[k] + sreg.z, e3 = sn[k] + sreg.w;
            e0 = fmaxf(e0, ALPHA*e0); e1 = fmaxf(e1, ALPHA*e1);
            e2 = fmaxf(e2, ALPHA*e2); e3 = fmaxf(e3, ALPHA*e3);
            e0 = fminf(e0, 60.f); e1 = fminf(e1, 60.f);   // exp can never reach inf
            e2 = fminf(e2, 60.f); e3 = fminf(e3, 60.f);
            float p0 = mreg[k].x > 0 ? __expf(e0) : 0.f;
            float p1 = mreg[k].y > 0 ? __expf(e1) : 0.f;
            float p2 = mreg[k].z > 0 ? __expf(e2) : 0.f;
            float p3 = mreg[k].w > 0 ? __expf(e3) : 0.f;
            uint2 pv;
            pv.x = (u32)f2bf(p0) | ((u32)f2bf(p1) << 16);
            pv.y = (u32)f2bf(p2) | ((u32)f2bf(p3) << 16);
            *(uint2*)&p_lds[r][lane*4] = pv;
        }
        __syncthreads();

        // prefetch next chunk (overlaps MFMA phase)
        const int chn = ch + 1;
        if (chn < CHUNKS){
#pragma unroll
            for (int k = 0; k < 2; k++)
                mreg[k] = *(const int4*)(mask + (size_t)(b0 + wv + 8*k) * N_COLS + chn*NC + lane*4);
            sreg = *(const float4*)(s_neigh + chn*NC + lane*4);
        }

        // ---- phase 2: MFMA over this chunk (K = NC) ----
        const short8* hb8 = (const short8*)hB;
#pragma unroll
        for (int ks = 0; ks < NC/32; ks++){
            short8 afrag = *(const short8*)&p_lds[m][ks*32 + q*8];   // A[m][k=q*8+j]
            const int kb = ch*32 + ks*4 + q;
            short8 bfr = hb8[kb * OUT_DIM + c0 + m];                 // B[k=q*8+j][col]
            acc = __builtin_amdgcn_mfma_f32_16x16x32_bf16(afrag, bfr, acc, 0, 0, 0);
        }
        __syncthreads();
    }

    // ---- fused L2 normalize: rowsum of v^2 across the block ----
    // C/D layout: col = lane&15 (c0+m), row = q*4 + reg
#pragma unroll
    for (int reg = 0; reg < 4; reg++){
        float p = acc[reg] * acc[reg];
        p += __shfl_xor(p, 8); p += __shfl_xor(p, 4);
        p += __shfl_xor(p, 2); p += __shfl_xor(p, 1);
        if (m == 0) rs[wv][q*4 + reg] = p;
    }
    __syncthreads();

    const int isbf = *flag;
#pragma unroll
    for (int reg = 0; reg < 4; reg++){
        const int row = q*4 + reg;
        float tot = 0.f;
#pragma unroll
        for (int w = 0; w < 8; w++) tot += rs[w][row];
        float scale = 1.f / fmaxf(sqrtf(tot), 1e-12f);
        float v = acc[reg] * scale;
        size_t idx = (size_t)(b0 + row) * OUT_DIM + c0 + m;
        if (isbf) ((u16*)out)[idx] = f2bf(v);
        else      ((float*)out)[idx] = v;
    }
}

extern "C" void kernel_launch(void* const* d_in, const int* in_sizes, int n_in,
                              void* d_out, int out_size, void* d_ws, size_t ws_size,
                              hipStream_t stream){
    const void* gf    = d_in[0];
    const int*  nodes = (const int*)d_in[1];
    const int*  uniq  = (const int*)d_in[2];
    const int*  mask  = (const int*)d_in[3];
    const void* W     = d_in[4];
    const void* a1    = d_in[5];
    const void* a2    = d_in[6];

    char* ws = (char*)d_ws;
    u16*   hB      = (u16*)ws;                                 // 2 MB
    float* s_neigh = (float*)(ws + (2u<<20));                  // 32 KB
    float* s_node  = (float*)(ws + (2u<<20) + (32u<<10));      // 16 KB
    float* Wa1     = (float*)(ws + (2u<<20) + (48u<<10));      // 1 KB
    int*   flag    = (int*)  (ws + (2u<<20) + (50u<<10));      // 4 B

    hipLaunchKernelGGL(k_detect, dim3(1),          dim3(256), 0, stream, (const u32*)gf, flag);
    hipLaunchKernelGGL(k_wa,     dim3(1),          dim3(256), 0, stream, W, a1, flag, Wa1);
    hipLaunchKernelGGL(k_hneigh, dim3(N_COLS/8),   dim3(128), 0, stream, gf, uniq, W, a2, flag, hB, s_neigh);
    hipLaunchKernelGGL(k_snode,  dim3(B_ROWS/4),   dim3(256), 0, stream, gf, nodes, Wa1, flag, s_node);
    hipLaunchKernelGGL(k_attn,   dim3(B_ROWS/BT),  dim3(512), 0, stream, mask, s_node, s_neigh, hB, flag, d_out);
}

// Round 4
// 314.676 us; speedup vs baseline: 1.1901x; 1.1901x over previous
//
#include <hip/hip_runtime.h>

#define IN_DIM  256
#define OUT_DIM 128
#define B_ROWS  4096
#define N_COLS  8192
#define ALPHA   0.2f

typedef unsigned short u16;
typedef unsigned int   u32;
typedef __attribute__((ext_vector_type(8))) short short8;
typedef __attribute__((ext_vector_type(4))) float floatx4;

__device__ __forceinline__ float bf2f(u16 v){ return __uint_as_float(((u32)v) << 16); }
__device__ __forceinline__ float bflo(u32 v){ return __uint_as_float(v << 16); }
__device__ __forceinline__ float bfhi(u32 v){ return __uint_as_float(v & 0xffff0000u); }
__device__ __forceinline__ u16 f2bf(float f){
    u32 u = __float_as_uint(f);
    u += 0x7fffu + ((u >> 16) & 1u);       // round-to-nearest-even
    return (u16)(u >> 16);
}

// ---------- dtype detection: bf16-packed vs float32 ----------
__global__ __launch_bounds__(256) void k_detect(const u32* __restrict__ g, int* __restrict__ flag){
    __shared__ int votes[256];
    int t = threadIdx.x;
    u32 u = g[t];
    int e = (u >> 7) & 0xFF;
    votes[t] = (e >= 110 && e <= 140) ? 1 : 0;
    __syncthreads();
    for (int s = 128; s > 0; s >>= 1){
        if (t < s) votes[t] += votes[t + s];
        __syncthreads();
    }
    if (t == 0) flag[0] = (votes[0] >= 128) ? 1 : 0;   // 1 = bf16
}

// ---------------- Wa1 = W @ a1  (256 floats) ----------------
__global__ __launch_bounds__(256) void k_wa(const void* __restrict__ W, const void* __restrict__ a1,
                                            const int* __restrict__ flag, float* __restrict__ Wa1){
    __shared__ float a1s[OUT_DIM];
    int t = threadIdx.x;
    const int isbf = *flag;
    if (t < OUT_DIM) a1s[t] = isbf ? bf2f(((const u16*)a1)[t]) : ((const float*)a1)[t];
    __syncthreads();
    float s = 0.f;
    if (isbf){
        const u32* wr = (const u32*)W + t * (OUT_DIM/2);
#pragma unroll 8
        for (int i = 0; i < OUT_DIM/2; i++){
            u32 g = wr[i];
            s += bflo(g) * a1s[2*i] + bfhi(g) * a1s[2*i+1];
        }
    } else {
        const float* wr = (const float*)W + t * OUT_DIM;
#pragma unroll 8
        for (int c = 0; c < OUT_DIM; c++) s += wr[c] * a1s[c];
    }
    Wa1[t] = s;
}

// ------- WB: W -> bf16 B-frag layout WB[(k>>3)*1024 + c*8 + (k&7)]; + a2f -------
__global__ __launch_bounds__(128) void k_wb(const void* __restrict__ W, const void* __restrict__ a2,
                                            const int* __restrict__ flag,
                                            u16* __restrict__ WB, float* __restrict__ a2f){
    const int c  = threadIdx.x;
    const int kb = blockIdx.x;           // 32 k-blocks of 8
    const int isbf = *flag;
    short8 v;
#pragma unroll
    for (int j = 0; j < 8; j++){
        float w = isbf ? bf2f(((const u16*)W)[(kb*8 + j) * OUT_DIM + c])
                       : ((const float*)W)[(kb*8 + j) * OUT_DIM + c];
        v[j] = (short)f2bf(w);
    }
    ((short8*)WB)[kb * OUT_DIM + c] = v;
    if (kb == 0) a2f[c] = isbf ? bf2f(((const u16*)a2)[c]) : ((const float*)a2)[c];
}

// ------- h_neigh = gf[uniq] @ W via MFMA -> hB blocked bf16 + s_neigh = h @ a2 -------
// hB layout: u16 hB[(n>>3)*1024 + c*8 + (n&7)]
__global__ __launch_bounds__(256) void k_hneigh(const void* __restrict__ gf, const int* __restrict__ uniq,
                                                const u16* __restrict__ WB, const float* __restrict__ a2f,
                                                const int* __restrict__ flag,
                                                u16* __restrict__ hB, float* __restrict__ s_neigh){
    const int n0   = blockIdx.x * 16;     // 16 neighbor rows per block
    const int t    = threadIdx.x;
    const int lane = t & 63;
    const int wv   = t >> 6;              // 4 waves, wave handles col-blocks wv*2, wv*2+1
    const int q    = lane >> 4;
    const int m    = lane & 15;
    const int isbf = *flag;
    const int jb0  = wv * 2;

    const size_t row = (size_t)uniq[n0 + m];
    const short8* wb8 = (const short8*)WB;

    floatx4 acc0 = {0.f,0.f,0.f,0.f};
    floatx4 acc1 = {0.f,0.f,0.f,0.f};

#pragma unroll
    for (int ks = 0; ks < IN_DIM/32; ks++){
        short8 afrag;
        if (isbf){
            afrag = *(const short8*)((const u16*)gf + row * IN_DIM + ks*32 + q*8);
        } else {
            const float* gp = (const float*)gf + row * IN_DIM + ks*32 + q*8;
            float4 f0 = *(const float4*)gp;
            float4 f1 = *(const float4*)(gp + 4);
            afrag[0] = (short)f2bf(f0.x); afrag[1] = (short)f2bf(f0.y);
            afrag[2] = (short)f2bf(f0.z); afrag[3] = (short)f2bf(f0.w);
            afrag[4] = (short)f2bf(f1.x); afrag[5] = (short)f2bf(f1.y);
            afrag[6] = (short)f2bf(f1.z); afrag[7] = (short)f2bf(f1.w);
        }
        const int kb = ks*4 + q;
        short8 b0 = wb8[kb * OUT_DIM + jb0*16 + m];
        short8 b1 = wb8[kb * OUT_DIM + (jb0+1)*16 + m];
        acc0 = __builtin_amdgcn_mfma_f32_16x16x32_bf16(afrag, b0, acc0, 0, 0, 0);
        acc1 = __builtin_amdgcn_mfma_f32_16x16x32_bf16(afrag, b1, acc1, 0, 0, 0);
    }

    // C-layout: row = q*4+reg (neighbor n0+row), col = jb*16+m
    // store hB: lane writes 4 consecutive bf16 (rows) at (n0/8 + (q>>1))*1024 + c*8 + (q&1)*4
    {
        u32 lo0 = (u32)f2bf(acc0[0]) | ((u32)f2bf(acc0[1]) << 16);
        u32 hi0 = (u32)f2bf(acc0[2]) | ((u32)f2bf(acc0[3]) << 16);
        u32 lo1 = (u32)f2bf(acc1[0]) | ((u32)f2bf(acc1[1]) << 16);
        u32 hi1 = (u32)f2bf(acc1[2]) | ((u32)f2bf(acc1[3]) << 16);
        uint2 v0; v0.x = lo0; v0.y = hi0;
        uint2 v1; v1.x = lo1; v1.y = hi1;
        u16* base = hB + (size_t)(n0/8 + (q>>1)) * 1024 + (q&1)*4;
        *(uint2*)(base + (jb0*16 + m) * 8)     = v0;
        *(uint2*)(base + ((jb0+1)*16 + m) * 8) = v1;
    }

    // s_neigh partials: reduce over cols
    __shared__ float sred[4][16];
    float a2c0 = a2f[jb0*16 + m], a2c1 = a2f[(jb0+1)*16 + m];
#pragma unroll
    for (int reg = 0; reg < 4; reg++){
        float pr = acc0[reg]*a2c0 + acc1[reg]*a2c1;
        pr += __shfl_xor(pr, 1); pr += __shfl_xor(pr, 2);
        pr += __shfl_xor(pr, 4); pr += __shfl_xor(pr, 8);
        if (m == 0) sred[wv][q*4 + reg] = pr;
    }
    __syncthreads();
    if (t < 16) s_neigh[n0 + t] = sred[0][t] + sred[1][t] + sred[2][t] + sred[3][t];
}

// ---------------- s_node[b] = gf[nodes[b]] . Wa1 ----------------
__global__ __launch_bounds__(256) void k_snode(const void* __restrict__ gf, const int* __restrict__ nodes,
                                               const float* __restrict__ Wa1, const int* __restrict__ flag,
                                               float* __restrict__ s_node){
    int lane = threadIdx.x & 63, wv = threadIdx.x >> 6;
    int b = blockIdx.x * 4 + wv;
    const int isbf = *flag;
    float4 wa = ((const float4*)Wa1)[lane];
    float x0, x1, x2, x3;
    if (isbf){
        uint2 gg = ((const uint2*)((const u16*)gf + (size_t)nodes[b] * IN_DIM))[lane];
        x0 = bflo(gg.x); x1 = bfhi(gg.x); x2 = bflo(gg.y); x3 = bfhi(gg.y);
    } else {
        float4 gg = ((const float4*)((const float*)gf + (size_t)nodes[b] * IN_DIM))[lane];
        x0 = gg.x; x1 = gg.y; x2 = gg.z; x3 = gg.w;
    }
    float s = x0*wa.x + x1*wa.y + x2*wa.z + x3*wa.w;
    for (int off = 32; off > 0; off >>= 1) s += __shfl_down(s, off);
    if (lane == 0) s_node[b] = s;
}

// -------- main: out[b][c] = normalize_row( sum_n p(b,n) * h[n][c] ) --------
// 512 threads = 8 waves. Block owns 16 rows x 128 cols; waves split N 8-way.
// NO barriers in the K-loop: each wave builds its A-frag in registers.
__global__ __launch_bounds__(512, 2) void k_attn(const int* __restrict__ mask,
                                                 const float* __restrict__ s_node,
                                                 const float* __restrict__ s_neigh,
                                                 const u16* __restrict__ hB,
                                                 const int* __restrict__ flag,
                                                 void* __restrict__ out){
    const int b0   = blockIdx.x * 16;
    const int t    = threadIdx.x;
    const int lane = t & 63;
    const int wv   = t >> 6;                    // 0..7
    const int q    = lane >> 4;
    const int m    = lane & 15;

    const int n0   = wv * (N_COLS/8);           // wave's n-range: 1024
    const int KS   = (N_COLS/8) / 32;           // 32 ksteps

    floatx4 acc[8];
#pragma unroll
    for (int jb = 0; jb < 8; jb++){ floatx4 z = {0.f,0.f,0.f,0.f}; acc[jb] = z; }

    const float sn = s_node[b0 + m];            // this lane's row
    const int rowoff = (b0 + m) * N_COLS;
    const short8* hb8 = (const short8*)hB;

    for (int ks = 0; ks < KS; ks++){
        const int nb = n0 + ks*32 + q*8;
        int4   ma = *(const int4*)  (mask    + rowoff + nb);
        int4   mb = *(const int4*)  (mask    + rowoff + nb + 4);
        float4 sa = *(const float4*)(s_neigh + nb);
        float4 sb = *(const float4*)(s_neigh + nb + 4);

        float e[8] = { sn+sa.x, sn+sa.y, sn+sa.z, sn+sa.w,
                       sn+sb.x, sn+sb.y, sn+sb.z, sn+sb.w };
        int mk[8] = { ma.x, ma.y, ma.z, ma.w, mb.x, mb.y, mb.z, mb.w };
        short8 afrag;
#pragma unroll
        for (int j = 0; j < 8; j++){
            float ee = fmaxf(e[j], ALPHA*e[j]);
            ee = fminf(ee, 60.f);                      // exp never overflows
            float p = mk[j] > 0 ? __expf(ee) : 0.f;
            afrag[j] = (short)f2bf(p);
        }

        const int kb = ((n0 + ks*32) >> 3) + q;
#pragma unroll
        for (int jb = 0; jb < 8; jb++){
            short8 bfr = hb8[kb * OUT_DIM + jb*16 + m];
            acc[jb] = __builtin_amdgcn_mfma_f32_16x16x32_bf16(afrag, bfr, acc[jb], 0, 0, 0);
        }
    }

    // ---- cross-wave combine + fused L2 normalize ----
    __shared__ float red[8][16][128];               // 64 KB
#pragma unroll
    for (int jb = 0; jb < 8; jb++)
#pragma unroll
        for (int reg = 0; reg < 4; reg++)
            red[wv][q*4 + reg][jb*16 + m] = acc[jb][reg];
    __syncthreads();

    const int c  = t & 127;
    const int rp = t >> 7;                          // 0..3 -> rows rp*4..rp*4+3
    const int half = (t >> 6) & 1;

    float v[4];
#pragma unroll
    for (int i = 0; i < 4; i++){
        const int r = rp*4 + i;
        float s = 0.f;
#pragma unroll
        for (int w = 0; w < 8; w++) s += red[w][r][c];
        v[i] = s;
    }

    __shared__ float rs[16][2];
#pragma unroll
    for (int i = 0; i < 4; i++){
        float p = v[i] * v[i];
        p += __shfl_xor(p, 1);  p += __shfl_xor(p, 2);  p += __shfl_xor(p, 4);
        p += __shfl_xor(p, 8);  p += __shfl_xor(p, 16); p += __shfl_xor(p, 32);
        if (lane == 0) rs[rp*4 + i][half] = p;
    }
    __syncthreads();

    const int isbf = *flag;
#pragma unroll
    for (int i = 0; i < 4; i++){
        const int r = rp*4 + i;
        float tot = rs[r][0] + rs[r][1];
        float scale = 1.f / fmaxf(sqrtf(tot), 1e-12f);
        float o = v[i] * scale;
        size_t idx = (size_t)(b0 + r) * OUT_DIM + c;
        if (isbf) ((u16*)out)[idx] = f2bf(o);
        else      ((float*)out)[idx] = o;
    }
}

extern "C" void kernel_launch(void* const* d_in, const int* in_sizes, int n_in,
                              void* d_out, int out_size, void* d_ws, size_t ws_size,
                              hipStream_t stream){
    const void* gf    = d_in[0];
    const int*  nodes = (const int*)d_in[1];
    const int*  uniq  = (const int*)d_in[2];
    const int*  mask  = (const int*)d_in[3];
    const void* W     = d_in[4];
    const void* a1    = d_in[5];
    const void* a2    = d_in[6];

    char* ws = (char*)d_ws;
    u16*   hB      = (u16*)ws;                                  // 2 MB
    u16*   WB      = (u16*)(ws + (2u<<20));                     // 64 KB
    float* s_neigh = (float*)(ws + (2u<<20) + (64u<<10));       // 32 KB
    float* s_node  = (float*)(ws + (2u<<20) + (96u<<10));       // 16 KB
    float* Wa1     = (float*)(ws + (2u<<20) + (112u<<10));      // 1 KB
    float* a2f     = (float*)(ws + (2u<<20) + (113u<<10));      // 512 B
    int*   flag    = (int*)  (ws + (2u<<20) + (114u<<10));      // 4 B

    hipLaunchKernelGGL(k_detect, dim3(1),           dim3(256), 0, stream, (const u32*)gf, flag);
    hipLaunchKernelGGL(k_wa,     dim3(1),           dim3(256), 0, stream, W, a1, flag, Wa1);
    hipLaunchKernelGGL(k_wb,     dim3(32),          dim3(128), 0, stream, W, a2, flag, WB, a2f);
    hipLaunchKernelGGL(k_snode,  dim3(B_ROWS/4),    dim3(256), 0, stream, gf, nodes, Wa1, flag, s_node);
    hipLaunchKernelGGL(k_hneigh, dim3(N_COLS/16),   dim3(256), 0, stream, gf, uniq, WB, a2f, flag, hB, s_neigh);
    hipLaunchKernelGGL(k_attn,   dim3(B_ROWS/16),   dim3(512), 0, stream, mask, s_node, s_neigh, hB, flag, d_out);
}